// Round 1
// baseline (994.055 us; speedup 1.0000x reference)
//
#include <hip/hip_runtime.h>

// EmbeddingSumConcat: B=4096 bags x F=32 columns, V=100000 rows/table,
// L=20 max bag length, E=64 emb dim. One wave64 per (b,f) bag:
// lane e accumulates element e; ids preloaded by lanes 0..19 and
// broadcast via __shfl so the gather loads are independent (MLP).

#define BB 4096
#define FF 32
#define VV 100000
#define LL 20
#define EE 64

__global__ __launch_bounds__(256) void emb_bag_sum_kernel(
    const int* __restrict__ ids,      // [B, F, L] int32
    const int* __restrict__ lengths,  // [B, F]    int32
    const float* __restrict__ tables, // [F, V, E] f32
    float* __restrict__ out)          // [B, F*E]  f32
{
    const int wave = threadIdx.x >> 6;           // 4 waves per block
    const int lane = threadIdx.x & 63;
    const int bag  = (blockIdx.x << 2) + wave;   // bag = b*F + f, in [0, B*F)
    const int f    = bag & (FF - 1);

    const int len = lengths[bag];
    const int* __restrict__ idp = ids + (long)bag * LL;
    const float* __restrict__ tab = tables + (long)f * VV * EE;

    // Cooperative id preload: lanes 0..19 each grab one id (single coalesced
    // 80B load for the wave), then broadcast per-l via shfl. This removes the
    // serial uniform-load chain and lets the 20 gathers overlap.
    int myid = 0;
    if (lane < LL) myid = idp[lane];

    float acc = 0.0f;
    for (int l = 0; l < len; ++l) {
        const int id = __shfl(myid, l);          // wave-uniform broadcast
        acc += tab[(long)id * EE + lane];        // 64 lanes x 4B = 256B row
    }

    out[(long)bag * EE + lane] = acc;            // coalesced store
}

extern "C" void kernel_launch(void* const* d_in, const int* in_sizes, int n_in,
                              void* d_out, int out_size, void* d_ws, size_t ws_size,
                              hipStream_t stream) {
    const int*   ids     = (const int*)d_in[0];
    const int*   lengths = (const int*)d_in[1];
    const float* tables  = (const float*)d_in[2];
    float*       out     = (float*)d_out;

    const int n_bags = BB * FF;                  // 131072
    const int blocks = n_bags / 4;               // 4 waves (bags) per 256-thread block
    emb_bag_sum_kernel<<<blocks, 256, 0, stream>>>(ids, lengths, tables, out);
}

// Round 2
// 937.439 us; speedup vs baseline: 1.0604x; 1.0604x over previous
//
#include <hip/hip_runtime.h>

// EmbeddingSumConcat: B=4096 x F=32 bags, V=100000, L=20, E=64.
// One wave64 per (b,f) bag; lane e owns output element e.
//
// Round-1 lesson: runtime-trip-count loop serialized the gathers
// (1 load in flight/wave -> 994 us, ~5% HBM BW). Round 2: fully unroll
// L=20 with index clamped to min(l, len-1) -- ids[] is fully populated
// with valid indices, so over-length loads are safe and L1-cached --
// and mask the accumulate. All 20 global_loads issue back-to-back
// (MLP ~20) before the first vmcnt wait.

#define BB 4096
#define FF 32
#define VV 100000
#define LL 20
#define EE 64

__global__ __launch_bounds__(256) void emb_bag_sum_kernel(
    const int* __restrict__ ids,      // [B, F, L] int32
    const int* __restrict__ lengths,  // [B, F]    int32
    const float* __restrict__ tables, // [F, V, E] f32
    float* __restrict__ out)          // [B, F*E]  f32
{
    const int wave = threadIdx.x >> 6;           // 4 waves per block
    const int lane = threadIdx.x & 63;
    const int bag  = (blockIdx.x << 2) + wave;   // bag = b*F + f
    const int f    = bag & (FF - 1);

    const int len = lengths[bag];
    const int* __restrict__ idp = ids + bag * LL;            // fits int32
    const float* __restrict__ tab = tables + (size_t)f * (VV * EE);

    // Lanes 0..19 cooperatively load the 20 ids (one 80B coalesced load).
    int myid = (lane < LL) ? idp[lane] : 0;
    const int lastl = (len > 0) ? (len - 1) : 0;

    // Phase 1: all 20 offsets (clamped index -> always safe, dup rows L1-hit).
    int off[LL];
#pragma unroll
    for (int l = 0; l < LL; ++l) {
        const int sl = (l < len) ? l : lastl;    // wave-uniform
        const int id = __shfl(myid, sl);
        off[l] = (id << 6) + lane;               // id*64 + lane, < 6.4M: int32 ok
    }

    // Phase 2: 20 independent gathers, issued back-to-back.
    float v[LL];
#pragma unroll
    for (int l = 0; l < LL; ++l) v[l] = tab[off[l]];

    // Phase 3: masked accumulate.
    float acc = 0.0f;
#pragma unroll
    for (int l = 0; l < LL; ++l) acc += (l < len) ? v[l] : 0.0f;

    out[bag * EE + lane] = acc;                  // coalesced 256B/wave store
}

extern "C" void kernel_launch(void* const* d_in, const int* in_sizes, int n_in,
                              void* d_out, int out_size, void* d_ws, size_t ws_size,
                              hipStream_t stream) {
    const int*   ids     = (const int*)d_in[0];
    const int*   lengths = (const int*)d_in[1];
    const float* tables  = (const float*)d_in[2];
    float*       out     = (float*)d_out;

    const int n_bags = BB * FF;                  // 131072
    const int blocks = n_bags / 4;               // 4 bags (waves) per block
    emb_bag_sum_kernel<<<blocks, 256, 0, stream>>>(ids, lengths, tables, out);
}